// Round 8
// baseline (679.747 us; speedup 1.0000x reference)
//
#include <hip/hip_runtime.h>

#define NGRAPH 100000
#define NEDGE  1600000
#define HID    128
#define SCAN_B 512
#define NBLK   ((NGRAPH + SCAN_B - 1) / SCAN_B)   // 196
#define TILE   64                                  // nodes per k_mlp block

// ---------- dtype detection: int64 edge_index has all-zero odd 32-bit words ----------
__global__ void k_detect(const int* __restrict__ ei, int* __restrict__ flag) {
    int t = threadIdx.x;                       // 64 threads
    int v = ei[2 * t + 1];                     // odd words of src region
    unsigned long long b = __ballot(v != 0);
    if (t == 0) flag[0] = (b == 0ull) ? 1 : 0; // 1 => int64, 0 => int32
}

__device__ __forceinline__ int e_src(const int* ei, int is64, int e) {
    return is64 ? ei[2 * e] : ei[e];
}
__device__ __forceinline__ int e_dst(const int* ei, int is64, int e) {
    return is64 ? ei[2 * NEDGE + 2 * e] : ei[NEDGE + e];
}

// ---------- combined features [NGRAPH][7]; deg (edge-only) = 0; fill = 0 ----------
__global__ void k_prep(const float* __restrict__ obs,
                       float* __restrict__ comb, int* __restrict__ deg,
                       int* __restrict__ fill) {
    int i = blockIdx.x * blockDim.x + threadIdx.x;
    if (i >= NGRAPH) return;
    int n = i / 20, c = i % 20;
    const float* nf = obs + 3 + n * 4;
    const float* cf = obs + 3 + 20000 + c * 3;
    float* o = comb + i * 7;
    o[0] = nf[0]; o[1] = nf[1]; o[2] = nf[2]; o[3] = nf[3];
    o[4] = cf[0]; o[5] = cf[1]; o[6] = cf[2];
    deg[i] = 0;
    fill[i] = 0;
}

__global__ void k_deg(const int* __restrict__ ei, const int* __restrict__ flag,
                      int* __restrict__ deg) {
    int e = blockIdx.x * blockDim.x + threadIdx.x;
    if (e >= NEDGE) return;
    atomicAdd(&deg[e_dst(ei, flag[0], e)], 1);
}

__global__ void k_dinv(const int* __restrict__ deg, float* __restrict__ dinv) {
    int i = blockIdx.x * blockDim.x + threadIdx.x;
    if (i >= NGRAPH) return;
    dinv[i] = rsqrtf((float)(deg[i] + 1));     // +1: self loop
}

// ---------- exclusive scan of deg -> rowptr (3-kernel hierarchical) ----------
__global__ void __launch_bounds__(SCAN_B) k_scan1(const int* __restrict__ deg,
                                                  int* __restrict__ rowptr,
                                                  int* __restrict__ sums) {
    __shared__ int sh[SCAN_B];
    int t = threadIdx.x;
    int i = blockIdx.x * SCAN_B + t;
    int val = (i < NGRAPH) ? deg[i] : 0;
    sh[t] = val;
    __syncthreads();
    for (int o = 1; o < SCAN_B; o <<= 1) {
        int x = (t >= o) ? sh[t - o] : 0;
        __syncthreads();
        sh[t] += x;
        __syncthreads();
    }
    if (i < NGRAPH) rowptr[i] = sh[t] - val;          // exclusive within block
    if (t == SCAN_B - 1) sums[blockIdx.x] = sh[t];    // block total
}

__global__ void __launch_bounds__(256) k_scan2(int* __restrict__ sums) {
    __shared__ int sh[256];
    int t = threadIdx.x;
    int val = (t < NBLK) ? sums[t] : 0;
    sh[t] = val;
    __syncthreads();
    for (int o = 1; o < 256; o <<= 1) {
        int x = (t >= o) ? sh[t - o] : 0;
        __syncthreads();
        sh[t] += x;
        __syncthreads();
    }
    if (t < NBLK) sums[t] = sh[t] - val;              // exclusive block offsets
}

__global__ void __launch_bounds__(SCAN_B) k_scan3(int* __restrict__ rowptr,
                                                  const int* __restrict__ sums) {
    int i = blockIdx.x * SCAN_B + threadIdx.x;
    if (i < NGRAPH) rowptr[i] += sums[blockIdx.x];
}

// ---------- scatter edges into CSR slots ----------
__global__ void k_fill(const int* __restrict__ ei, const int* __restrict__ flag,
                       const float* __restrict__ dinv,
                       const int* __restrict__ rowptr, int* __restrict__ fill,
                       int* __restrict__ csr_src, float* __restrict__ csr_w) {
    int e = blockIdx.x * blockDim.x + threadIdx.x;
    if (e >= NEDGE) return;
    int is64 = flag[0];
    int s = e_src(ei, is64, e);
    int d = e_dst(ei, is64, e);
    int pos = rowptr[d] + atomicAdd(&fill[d], 1);
    csr_src[pos] = s;
    csr_w[pos] = dinv[s] * dinv[d];
}

// ---------- fused GCN layer 1: CSR agg (7-dim) + [7->128] matmul + ReLU ----------
// 32 nodes/block, 8 lanes/node. Phase 1: lane f<7 aggregates feature f into LDS.
// Phase 2: lane f computes x1[d][f*16 .. f*16+15] from the LDS aggregate.
__global__ void __launch_bounds__(256) k_gcn1(const int* __restrict__ rowptr,
                                              const int* __restrict__ deg,
                                              const int* __restrict__ csr_src,
                                              const float* __restrict__ csr_w,
                                              const float* __restrict__ dinv,
                                              const float* __restrict__ comb,
                                              const float* __restrict__ W1,
                                              const float* __restrict__ b1,
                                              float* __restrict__ x1) {
    __shared__ float agg_s[32][8];
    int g = threadIdx.x >> 3;                  // node within block
    int f = threadIdx.x & 7;
    int d = blockIdx.x * 32 + g;
    if (f < 7) {
        int start = rowptr[d], n = deg[d];
        float acc = 0.0f;
        for (int j = 0; j < n; ++j) {
            int s = csr_src[start + j];
            float w = csr_w[start + j];
            acc += w * comb[s * 7 + f];
        }
        float dv = dinv[d];
        acc += dv * dv * comb[d * 7 + f];      // self loop
        agg_s[g][f] = acc;
    }
    __syncthreads();
    float a[7];
    #pragma unroll
    for (int q = 0; q < 7; ++q) a[q] = agg_s[g][q];   // LDS broadcast per node
    int h0 = f * 16;
    #pragma unroll
    for (int j = 0; j < 4; ++j) {
        int h = h0 + j * 4;
        float4 acc4 = *reinterpret_cast<const float4*>(b1 + h);
        #pragma unroll
        for (int q = 0; q < 7; ++q) {
            float4 w = *reinterpret_cast<const float4*>(W1 + q * HID + h);
            acc4.x += a[q] * w.x;
            acc4.y += a[q] * w.y;
            acc4.z += a[q] * w.z;
            acc4.w += a[q] * w.w;
        }
        acc4.x = fmaxf(acc4.x, 0.0f); acc4.y = fmaxf(acc4.y, 0.0f);
        acc4.z = fmaxf(acc4.z, 0.0f); acc4.w = fmaxf(acc4.w, 0.0f);
        *reinterpret_cast<float4*>(x1 + (size_t)d * HID + h) = acc4;
    }
}

// ---------- layer-2 agg over CSR: 1 wave/node, lane holds 2 of 128 feats ----------
__global__ void __launch_bounds__(256) k_agg2(const int* __restrict__ rowptr,
                                              const int* __restrict__ deg,
                                              const int* __restrict__ csr_src,
                                              const float* __restrict__ csr_w,
                                              const float* __restrict__ dinv,
                                              const float* __restrict__ x1,
                                              float* __restrict__ agg2) {
    int wave = threadIdx.x >> 6;
    int lane = threadIdx.x & 63;
    int d = blockIdx.x * 4 + wave;
    int f0 = lane * 2;
    int start = rowptr[d], n = deg[d];
    float2 acc = {0.0f, 0.0f};
    for (int j = 0; j < n; ++j) {
        int s = csr_src[start + j];        // same addr across wave -> broadcast
        float w = csr_w[start + j];
        float2 v = *reinterpret_cast<const float2*>(x1 + (size_t)s * HID + f0);
        acc.x += w * v.x;
        acc.y += w * v.y;
    }
    float dv = dinv[d];
    float ws = dv * dv;
    float2 v = *reinterpret_cast<const float2*>(x1 + (size_t)d * HID + f0);
    acc.x += ws * v.x;
    acc.y += ws * v.y;
    *reinterpret_cast<float2*>(agg2 + (size_t)d * HID + f0) = acc;
}

// ---------- fused dense tail: x2=relu(agg2@W2+b2); x3=relu(x2@fc1+b); out=x3@fc2+b ----
// Block = 256 threads = (32 tx: h0=tx*4) x (8 ty: 8 nodes each). 64 nodes/block.
// Per-wave weight streaming is fixed (64KB/phase); TILE=64 halves total wave count
// vs TILE=32 -> weight L2 traffic 3.2GB -> 1.6GB (k_l2-era lesson: L2-delivery-bound).
__device__ __forceinline__ void fma4(float4& acc, const float4 a,
                                     const float4 w0, const float4 w1,
                                     const float4 w2, const float4 w3) {
    acc.x += a.x * w0.x + a.y * w1.x + a.z * w2.x + a.w * w3.x;
    acc.y += a.x * w0.y + a.y * w1.y + a.z * w2.y + a.w * w3.y;
    acc.z += a.x * w0.z + a.y * w1.z + a.z * w2.z + a.w * w3.z;
    acc.w += a.x * w0.w + a.y * w1.w + a.z * w2.w + a.w * w3.w;
}
__device__ __forceinline__ float4 relu4(float4 v) {
    float4 r;
    r.x = fmaxf(v.x, 0.0f); r.y = fmaxf(v.y, 0.0f);
    r.z = fmaxf(v.z, 0.0f); r.w = fmaxf(v.w, 0.0f);
    return r;
}

__global__ void __launch_bounds__(256) k_mlp(const float* __restrict__ agg2,
                                             const float* __restrict__ W2,
                                             const float* __restrict__ b2,
                                             const float* __restrict__ fc1w,
                                             const float* __restrict__ fc1b,
                                             const float* __restrict__ fc2w,
                                             const float* __restrict__ fc2b,
                                             float* __restrict__ out) {
    __shared__ float xs[TILE][HID + 4];   // 64 x 132 x 4B = 33.8 KB -> 4 blocks/CU
    const int tx = threadIdx.x & 31;      // output group: h0 = tx*4
    const int ty = threadIdx.x >> 5;      // node group: nodes ty*8 .. ty*8+7
    const int n0 = blockIdx.x * TILE;
    const int h0 = tx * 4;

    // clamped row pointers (tail block reads node NGRAPH-1; writes are guarded)
    const float* ar[8];
    #pragma unroll
    for (int r = 0; r < 8; ++r) {
        int nr = n0 + ty * 8 + r;
        ar[r] = agg2 + (size_t)(nr < NGRAPH ? nr : NGRAPH - 1) * HID;
    }

    // ---- phase A: x2 tile = relu(agg2 @ W2 + b2) ----
    float4 bias = *reinterpret_cast<const float4*>(b2 + h0);
    float4 c[8];
    #pragma unroll
    for (int r = 0; r < 8; ++r) c[r] = bias;
    for (int k = 0; k < HID; k += 4) {
        float4 w0 = *reinterpret_cast<const float4*>(W2 + (k + 0) * HID + h0);
        float4 w1 = *reinterpret_cast<const float4*>(W2 + (k + 1) * HID + h0);
        float4 w2 = *reinterpret_cast<const float4*>(W2 + (k + 2) * HID + h0);
        float4 w3 = *reinterpret_cast<const float4*>(W2 + (k + 3) * HID + h0);
        #pragma unroll
        for (int r = 0; r < 8; ++r) {
            float4 a = *reinterpret_cast<const float4*>(ar[r] + k);
            fma4(c[r], a, w0, w1, w2, w3);
        }
    }
    #pragma unroll
    for (int r = 0; r < 8; ++r)
        *reinterpret_cast<float4*>(&xs[ty * 8 + r][h0]) = relu4(c[r]);
    __syncthreads();

    // ---- phase B: x3 = relu(x2 @ fc1w + fc1b) ----
    float4 bias1 = *reinterpret_cast<const float4*>(fc1b + h0);
    float4 dacc[8];
    #pragma unroll
    for (int r = 0; r < 8; ++r) dacc[r] = bias1;
    for (int k = 0; k < HID; k += 4) {
        float4 w0 = *reinterpret_cast<const float4*>(fc1w + (k + 0) * HID + h0);
        float4 w1 = *reinterpret_cast<const float4*>(fc1w + (k + 1) * HID + h0);
        float4 w2 = *reinterpret_cast<const float4*>(fc1w + (k + 2) * HID + h0);
        float4 w3 = *reinterpret_cast<const float4*>(fc1w + (k + 3) * HID + h0);
        #pragma unroll
        for (int r = 0; r < 8; ++r) {
            float4 a = *reinterpret_cast<const float4*>(&xs[ty * 8 + r][k]);
            fma4(dacc[r], a, w0, w1, w2, w3);
        }
    }

    // ---- phase C: out = x3 @ fc2w + fc2b (reduce over h across the 32 tx lanes) ----
    float4 wq = *reinterpret_cast<const float4*>(fc2w + h0);
    float p[8];
    #pragma unroll
    for (int r = 0; r < 8; ++r) {
        float4 dr = relu4(dacc[r]);
        p[r] = dr.x * wq.x + dr.y * wq.y + dr.z * wq.z + dr.w * wq.w;
    }
    #pragma unroll
    for (int m = 1; m < 32; m <<= 1) {     // xor-mask < 32 stays within the tx half
        #pragma unroll
        for (int r = 0; r < 8; ++r) p[r] += __shfl_xor(p[r], m);
    }
    if (tx == 0) {
        float bq = fc2b[0];
        int nb = n0 + ty * 8;
        #pragma unroll
        for (int r = 0; r < 8; ++r)
            if (nb + r < NGRAPH) out[nb + r] = p[r] + bq;
    }
}

extern "C" void kernel_launch(void* const* d_in, const int* in_sizes, int n_in,
                              void* d_out, int out_size, void* d_ws, size_t ws_size,
                              hipStream_t stream) {
    const float* obs  = (const float*)d_in[0];
    const int*   ei   = (const int*)d_in[1];
    const float* W1   = (const float*)d_in[2];
    const float* b1   = (const float*)d_in[3];
    const float* W2   = (const float*)d_in[4];
    const float* b2   = (const float*)d_in[5];
    const float* fc1w = (const float*)d_in[6];
    const float* fc1b = (const float*)d_in[7];
    const float* fc2w = (const float*)d_in[8];
    const float* fc2b = (const float*)d_in[9];
    float* out = (float*)d_out;

    char* base = (char*)d_ws;
    size_t off = 0;
    auto take = [&](size_t bytes) {
        char* p = base + off;
        off += (bytes + 255) & ~(size_t)255;
        return p;
    };
    int*   deg     = (int*)take((size_t)NGRAPH * 4);
    int*   rowptr  = (int*)take((size_t)NGRAPH * 4);
    int*   fill    = (int*)take((size_t)NGRAPH * 4);
    int*   sums    = (int*)take((size_t)NBLK * 4);
    float* dinv    = (float*)take((size_t)NGRAPH * 4);
    int*   csr_src = (int*)take((size_t)NEDGE * 4);
    float* csr_w   = (float*)take((size_t)NEDGE * 4);
    float* comb    = (float*)take((size_t)NGRAPH * 7 * 4);
    float* x1      = (float*)take((size_t)NGRAPH * HID * 4);
    float* agg2    = (float*)take((size_t)NGRAPH * HID * 4);
    int*   flag    = (int*)take(256);

    k_detect<<<1, 64, 0, stream>>>(ei, flag);
    k_prep<<<(NGRAPH + 255) / 256, 256, 0, stream>>>(obs, comb, deg, fill);
    k_deg<<<(NEDGE + 255) / 256, 256, 0, stream>>>(ei, flag, deg);
    k_dinv<<<(NGRAPH + 255) / 256, 256, 0, stream>>>(deg, dinv);
    k_scan1<<<NBLK, SCAN_B, 0, stream>>>(deg, rowptr, sums);
    k_scan2<<<1, 256, 0, stream>>>(sums);
    k_scan3<<<NBLK, SCAN_B, 0, stream>>>(rowptr, sums);
    k_fill<<<(NEDGE + 255) / 256, 256, 0, stream>>>(ei, flag, dinv, rowptr, fill,
                                                    csr_src, csr_w);
    k_gcn1<<<NGRAPH / 32, 256, 0, stream>>>(rowptr, deg, csr_src, csr_w, dinv,
                                            comb, W1, b1, x1);
    k_agg2<<<NGRAPH / 4, 256, 0, stream>>>(rowptr, deg, csr_src, csr_w, dinv,
                                           x1, agg2);
    k_mlp<<<(NGRAPH + TILE - 1) / TILE, 256, 0, stream>>>(agg2, W2, b2,
                                                          fc1w, fc1b,
                                                          fc2w, fc2b, out);
}

// Round 10
// 546.236 us; speedup vs baseline: 1.2444x; 1.2444x over previous
//
#include <hip/hip_runtime.h>

#define NGRAPH 100000
#define NEDGE  1600000
#define HID    128
#define SCAN_B 512
#define NBLK   ((NGRAPH + SCAN_B - 1) / SCAN_B)   // 196
#define TILE   32                                  // nodes per k_mlp block

__device__ __forceinline__ int e_src(const int* ei, int is64, int e) {
    return is64 ? ei[2 * e] : ei[e];
}
__device__ __forceinline__ int e_dst(const int* ei, int is64, int e) {
    return is64 ? ei[2 * NEDGE + 2 * e] : ei[NEDGE + e];
}

// ---------- combined features + deg/fill init + int64-detect (block 0, wave 0) ----------
__global__ void k_prep(const float* __restrict__ obs, const int* __restrict__ ei,
                       float* __restrict__ comb, int* __restrict__ deg,
                       int* __restrict__ fill, int* __restrict__ flag) {
    if (blockIdx.x == 0 && threadIdx.x < 64) {
        int v = ei[2 * threadIdx.x + 1];           // odd words of src region
        unsigned long long b = __ballot(v != 0);
        if (threadIdx.x == 0) flag[0] = (b == 0ull) ? 1 : 0;  // 1 => int64
    }
    int i = blockIdx.x * blockDim.x + threadIdx.x;
    if (i >= NGRAPH) return;
    int n = i / 20, c = i % 20;
    const float* nf = obs + 3 + n * 4;
    const float* cf = obs + 3 + 20000 + c * 3;
    float* o = comb + i * 7;
    o[0] = nf[0]; o[1] = nf[1]; o[2] = nf[2]; o[3] = nf[3];
    o[4] = cf[0]; o[5] = cf[1]; o[6] = cf[2];
    deg[i] = 0;
    fill[i] = 0;
}

__global__ void k_deg(const int* __restrict__ ei, const int* __restrict__ flag,
                      int* __restrict__ deg) {
    int e = blockIdx.x * blockDim.x + threadIdx.x;
    if (e >= NEDGE) return;
    atomicAdd(&deg[e_dst(ei, flag[0], e)], 1);
}

// ---------- exclusive scan of deg -> rowptr (3-kernel hierarchical); also dinv ----------
__global__ void __launch_bounds__(SCAN_B) k_scan1(const int* __restrict__ deg,
                                                  int* __restrict__ rowptr,
                                                  int* __restrict__ sums,
                                                  float* __restrict__ dinv) {
    __shared__ int sh[SCAN_B];
    int t = threadIdx.x;
    int i = blockIdx.x * SCAN_B + t;
    int val = (i < NGRAPH) ? deg[i] : 0;
    if (i < NGRAPH) dinv[i] = rsqrtf((float)(val + 1));   // +1: self loop
    sh[t] = val;
    __syncthreads();
    for (int o = 1; o < SCAN_B; o <<= 1) {
        int x = (t >= o) ? sh[t - o] : 0;
        __syncthreads();
        sh[t] += x;
        __syncthreads();
    }
    if (i < NGRAPH) rowptr[i] = sh[t] - val;          // exclusive within block
    if (t == SCAN_B - 1) sums[blockIdx.x] = sh[t];    // block total
}

__global__ void __launch_bounds__(256) k_scan2(int* __restrict__ sums) {
    __shared__ int sh[256];
    int t = threadIdx.x;
    int val = (t < NBLK) ? sums[t] : 0;
    sh[t] = val;
    __syncthreads();
    for (int o = 1; o < 256; o <<= 1) {
        int x = (t >= o) ? sh[t - o] : 0;
        __syncthreads();
        sh[t] += x;
        __syncthreads();
    }
    if (t < NBLK) sums[t] = sh[t] - val;              // exclusive block offsets
}

__global__ void __launch_bounds__(SCAN_B) k_scan3(int* __restrict__ rowptr,
                                                  const int* __restrict__ sums) {
    int i = blockIdx.x * SCAN_B + threadIdx.x;
    if (i < NGRAPH) rowptr[i] += sums[blockIdx.x];
}

// ---------- scatter edges into CSR slots ----------
__global__ void k_fill(const int* __restrict__ ei, const int* __restrict__ flag,
                       const float* __restrict__ dinv,
                       const int* __restrict__ rowptr, int* __restrict__ fill,
                       int* __restrict__ csr_src, float* __restrict__ csr_w) {
    int e = blockIdx.x * blockDim.x + threadIdx.x;
    if (e >= NEDGE) return;
    int is64 = flag[0];
    int s = e_src(ei, is64, e);
    int d = e_dst(ei, is64, e);
    int pos = rowptr[d] + atomicAdd(&fill[d], 1);
    csr_src[pos] = s;
    csr_w[pos] = dinv[s] * dinv[d];
}

// ---------- fused GCN layer 1: CSR agg (7-dim) + [7->128] matmul + ReLU ----------
__global__ void __launch_bounds__(256) k_gcn1(const int* __restrict__ rowptr,
                                              const int* __restrict__ deg,
                                              const int* __restrict__ csr_src,
                                              const float* __restrict__ csr_w,
                                              const float* __restrict__ dinv,
                                              const float* __restrict__ comb,
                                              const float* __restrict__ W1,
                                              const float* __restrict__ b1,
                                              float* __restrict__ x1) {
    __shared__ float agg_s[32][8];
    int g = threadIdx.x >> 3;                  // node within block
    int f = threadIdx.x & 7;
    int d = blockIdx.x * 32 + g;
    if (f < 7) {
        int start = rowptr[d], n = deg[d];
        float acc = 0.0f;
        for (int j = 0; j < n; ++j) {
            int s = csr_src[start + j];
            float w = csr_w[start + j];
            acc += w * comb[s * 7 + f];
        }
        float dv = dinv[d];
        acc += dv * dv * comb[d * 7 + f];      // self loop
        agg_s[g][f] = acc;
    }
    __syncthreads();
    float a[7];
    #pragma unroll
    for (int q = 0; q < 7; ++q) a[q] = agg_s[g][q];   // LDS broadcast per node
    int h0 = f * 16;
    #pragma unroll
    for (int j = 0; j < 4; ++j) {
        int h = h0 + j * 4;
        float4 acc4 = *reinterpret_cast<const float4*>(b1 + h);
        #pragma unroll
        for (int q = 0; q < 7; ++q) {
            float4 w = *reinterpret_cast<const float4*>(W1 + q * HID + h);
            acc4.x += a[q] * w.x;
            acc4.y += a[q] * w.y;
            acc4.z += a[q] * w.z;
            acc4.w += a[q] * w.w;
        }
        acc4.x = fmaxf(acc4.x, 0.0f); acc4.y = fmaxf(acc4.y, 0.0f);
        acc4.z = fmaxf(acc4.z, 0.0f); acc4.w = fmaxf(acc4.w, 0.0f);
        *reinterpret_cast<float4*>(x1 + (size_t)d * HID + h) = acc4;
    }
}

// ---------- layer-2 agg over CSR: 1 wave/node, lane holds 2 of 128 feats ----------
// Edge loop unrolled x2: two independent row-gathers in flight per iteration.
__global__ void __launch_bounds__(256) k_agg2(const int* __restrict__ rowptr,
                                              const int* __restrict__ deg,
                                              const int* __restrict__ csr_src,
                                              const float* __restrict__ csr_w,
                                              const float* __restrict__ dinv,
                                              const float* __restrict__ x1,
                                              float* __restrict__ agg2) {
    int wave = threadIdx.x >> 6;
    int lane = threadIdx.x & 63;
    int d = blockIdx.x * 4 + wave;
    int f0 = lane * 2;
    int start = rowptr[d], n = deg[d];
    float2 acc = {0.0f, 0.0f};
    int j = 0;
    for (; j + 2 <= n; j += 2) {
        int s0 = csr_src[start + j];
        int s1 = csr_src[start + j + 1];
        float w0 = csr_w[start + j];
        float w1 = csr_w[start + j + 1];
        float2 v0 = *reinterpret_cast<const float2*>(x1 + (size_t)s0 * HID + f0);
        float2 v1 = *reinterpret_cast<const float2*>(x1 + (size_t)s1 * HID + f0);
        acc.x += w0 * v0.x + w1 * v1.x;
        acc.y += w0 * v0.y + w1 * v1.y;
    }
    if (j < n) {
        int s0 = csr_src[start + j];
        float w0 = csr_w[start + j];
        float2 v0 = *reinterpret_cast<const float2*>(x1 + (size_t)s0 * HID + f0);
        acc.x += w0 * v0.x;
        acc.y += w0 * v0.y;
    }
    float dv = dinv[d];
    float ws = dv * dv;
    float2 v = *reinterpret_cast<const float2*>(x1 + (size_t)d * HID + f0);
    acc.x += ws * v.x;
    acc.y += ws * v.y;
    *reinterpret_cast<float2*>(agg2 + (size_t)d * HID + f0) = acc;
}

// ---------- fused dense tail, fully LDS-resident inner loops ----------
// TILE=32 (occupancy lesson from r8: TILE=64 killed TLP). Activations (16KB) and
// 32-row weight chunks (16KB) staged cooperatively into LDS; inner loop reads LDS
// only (weights ~4-way bank alias = 1.58x, activations broadcast). x2 overwrites
// the activation buffer between phases. LDS = 33.8KB -> 4 blocks/CU = 16 waves/CU.
__device__ __forceinline__ void fma4(float4& acc, const float4 a,
                                     const float4 w0, const float4 w1,
                                     const float4 w2, const float4 w3) {
    acc.x += a.x * w0.x + a.y * w1.x + a.z * w2.x + a.w * w3.x;
    acc.y += a.x * w0.y + a.y * w1.y + a.z * w2.y + a.w * w3.y;
    acc.z += a.x * w0.z + a.y * w1.z + a.z * w2.z + a.w * w3.z;
    acc.w += a.x * w0.w + a.y * w1.w + a.z * w2.w + a.w * w3.w;
}
__device__ __forceinline__ float4 relu4(float4 v) {
    float4 r;
    r.x = fmaxf(v.x, 0.0f); r.y = fmaxf(v.y, 0.0f);
    r.z = fmaxf(v.z, 0.0f); r.w = fmaxf(v.w, 0.0f);
    return r;
}

__global__ void __launch_bounds__(256) k_mlp(const float* __restrict__ agg2,
                                             const float* __restrict__ W2,
                                             const float* __restrict__ b2,
                                             const float* __restrict__ fc1w,
                                             const float* __restrict__ fc1b,
                                             const float* __restrict__ fc2w,
                                             const float* __restrict__ fc2b,
                                             float* __restrict__ out) {
    __shared__ float as_[TILE][HID + 4];   // activation tile, then x2 tile
    __shared__ float ws[32][HID + 4];      // 32 staged weight rows
    const int tid = threadIdx.x;
    const int tx = tid & 31;               // h0 = tx*4
    const int ty = tid >> 5;               // nodes ty*4 .. ty*4+3
    const int n0 = blockIdx.x * TILE;      // 3125 blocks exactly, no tail
    const int h0 = tx * 4;

    // stage activations: rows n0..n0+31 are one contiguous 16KB block
    {
        const float* src = agg2 + (size_t)n0 * HID;
        #pragma unroll
        for (int q = 0; q < 4; ++q) {
            int idx = (q * 256 + tid) * 4;             // 0..4095 floats
            int row = idx >> 7, col = idx & 127;
            *reinterpret_cast<float4*>(&as_[row][col]) =
                *reinterpret_cast<const float4*>(src + idx);
        }
    }

    // ---- phase A: x2 = relu(agg2 @ W2 + b2), 32-row weight chunks ----
    float4 bias = *reinterpret_cast<const float4*>(b2 + h0);
    float4 c0 = bias, c1 = bias, c2 = bias, c3 = bias;
    for (int ks = 0; ks < HID; ks += 32) {
        const float* wsrc = W2 + (size_t)ks * HID;
        #pragma unroll
        for (int q = 0; q < 4; ++q) {
            int idx = (q * 256 + tid) * 4;
            int row = idx >> 7, col = idx & 127;
            *reinterpret_cast<float4*>(&ws[row][col]) =
                *reinterpret_cast<const float4*>(wsrc + idx);
        }
        __syncthreads();                    // also covers as_ staging on ks==0
        #pragma unroll 4
        for (int k = 0; k < 32; k += 4) {
            float4 w0 = *reinterpret_cast<const float4*>(&ws[k + 0][h0]);
            float4 w1 = *reinterpret_cast<const float4*>(&ws[k + 1][h0]);
            float4 w2 = *reinterpret_cast<const float4*>(&ws[k + 2][h0]);
            float4 w3 = *reinterpret_cast<const float4*>(&ws[k + 3][h0]);
            float4 a0 = *reinterpret_cast<const float4*>(&as_[ty * 4 + 0][ks + k]);
            float4 a1 = *reinterpret_cast<const float4*>(&as_[ty * 4 + 1][ks + k]);
            float4 a2 = *reinterpret_cast<const float4*>(&as_[ty * 4 + 2][ks + k]);
            float4 a3 = *reinterpret_cast<const float4*>(&as_[ty * 4 + 3][ks + k]);
            fma4(c0, a0, w0, w1, w2, w3);
            fma4(c1, a1, w0, w1, w2, w3);
            fma4(c2, a2, w0, w1, w2, w3);
            fma4(c3, a3, w0, w1, w2, w3);
        }
        __syncthreads();                    // protect ws for next stage
    }
    // write x2 into as_ (all phase-A reads done after trailing sync above)
    *reinterpret_cast<float4*>(&as_[ty * 4 + 0][h0]) = relu4(c0);
    *reinterpret_cast<float4*>(&as_[ty * 4 + 1][h0]) = relu4(c1);
    *reinterpret_cast<float4*>(&as_[ty * 4 + 2][h0]) = relu4(c2);
    *reinterpret_cast<float4*>(&as_[ty * 4 + 3][h0]) = relu4(c3);

    // ---- phase B: x3 = relu(x2 @ fc1w + fc1b) ----
    float4 bias1 = *reinterpret_cast<const float4*>(fc1b + h0);
    float4 d0 = bias1, d1 = bias1, d2 = bias1, d3 = bias1;
    for (int ks = 0; ks < HID; ks += 32) {
        const float* wsrc = fc1w + (size_t)ks * HID;
        #pragma unroll
        for (int q = 0; q < 4; ++q) {
            int idx = (q * 256 + tid) * 4;
            int row = idx >> 7, col = idx & 127;
            *reinterpret_cast<float4*>(&ws[row][col]) =
                *reinterpret_cast<const float4*>(wsrc + idx);
        }
        __syncthreads();                    // also makes x2 writes visible (ks==0)
        #pragma unroll 4
        for (int k = 0; k < 32; k += 4) {
            float4 w0 = *reinterpret_cast<const float4*>(&ws[k + 0][h0]);
            float4 w1 = *reinterpret_cast<const float4*>(&ws[k + 1][h0]);
            float4 w2 = *reinterpret_cast<const float4*>(&ws[k + 2][h0]);
            float4 w3 = *reinterpret_cast<const float4*>(&ws[k + 3][h0]);
            float4 a0 = *reinterpret_cast<const float4*>(&as_[ty * 4 + 0][ks + k]);
            float4 a1 = *reinterpret_cast<const float4*>(&as_[ty * 4 + 1][ks + k]);
            float4 a2 = *reinterpret_cast<const float4*>(&as_[ty * 4 + 2][ks + k]);
            float4 a3 = *reinterpret_cast<const float4*>(&as_[ty * 4 + 3][ks + k]);
            fma4(d0, a0, w0, w1, w2, w3);
            fma4(d1, a1, w0, w1, w2, w3);
            fma4(d2, a2, w0, w1, w2, w3);
            fma4(d3, a3, w0, w1, w2, w3);
        }
        __syncthreads();
    }

    // ---- phase C: out = x3 @ fc2w + fc2b (reduce over h across the 32 tx lanes) ----
    float4 wq = *reinterpret_cast<const float4*>(fc2w + h0);
    float4 r0 = relu4(d0), r1 = relu4(d1), r2 = relu4(d2), r3 = relu4(d3);
    float p0 = r0.x * wq.x + r0.y * wq.y + r0.z * wq.z + r0.w * wq.w;
    float p1 = r1.x * wq.x + r1.y * wq.y + r1.z * wq.z + r1.w * wq.w;
    float p2 = r2.x * wq.x + r2.y * wq.y + r2.z * wq.z + r2.w * wq.w;
    float p3 = r3.x * wq.x + r3.y * wq.y + r3.z * wq.z + r3.w * wq.w;
    #pragma unroll
    for (int m = 1; m < 32; m <<= 1) {     // xor-mask < 32 stays within the tx half
        p0 += __shfl_xor(p0, m);
        p1 += __shfl_xor(p1, m);
        p2 += __shfl_xor(p2, m);
        p3 += __shfl_xor(p3, m);
    }
    if (tx == 0) {
        float bq = fc2b[0];
        int nb = n0 + ty * 4;
        out[nb + 0] = p0 + bq;
        out[nb + 1] = p1 + bq;
        out[nb + 2] = p2 + bq;
        out[nb + 3] = p3 + bq;
    }
}

extern "C" void kernel_launch(void* const* d_in, const int* in_sizes, int n_in,
                              void* d_out, int out_size, void* d_ws, size_t ws_size,
                              hipStream_t stream) {
    const float* obs  = (const float*)d_in[0];
    const int*   ei   = (const int*)d_in[1];
    const float* W1   = (const float*)d_in[2];
    const float* b1   = (const float*)d_in[3];
    const float* W2   = (const float*)d_in[4];
    const float* b2   = (const float*)d_in[5];
    const float* fc1w = (const float*)d_in[6];
    const float* fc1b = (const float*)d_in[7];
    const float* fc2w = (const float*)d_in[8];
    const float* fc2b = (const float*)d_in[9];
    float* out = (float*)d_out;

    char* base = (char*)d_ws;
    size_t off = 0;
    auto take = [&](size_t bytes) {
        char* p = base + off;
        off += (bytes + 255) & ~(size_t)255;
        return p;
    };
    int*   deg     = (int*)take((size_t)NGRAPH * 4);
    int*   rowptr  = (int*)take((size_t)NGRAPH * 4);
    int*   fill    = (int*)take((size_t)NGRAPH * 4);
    int*   sums    = (int*)take((size_t)NBLK * 4);
    float* dinv    = (float*)take((size_t)NGRAPH * 4);
    int*   csr_src = (int*)take((size_t)NEDGE * 4);
    float* csr_w   = (float*)take((size_t)NEDGE * 4);
    float* comb    = (float*)take((size_t)NGRAPH * 7 * 4);
    float* x1      = (float*)take((size_t)NGRAPH * HID * 4);
    float* agg2    = (float*)take((size_t)NGRAPH * HID * 4);
    int*   flag    = (int*)take(256);

    k_prep<<<(NGRAPH + 255) / 256, 256, 0, stream>>>(obs, ei, comb, deg, fill, flag);
    k_deg<<<(NEDGE + 255) / 256, 256, 0, stream>>>(ei, flag, deg);
    k_scan1<<<NBLK, SCAN_B, 0, stream>>>(deg, rowptr, sums, dinv);
    k_scan2<<<1, 256, 0, stream>>>(sums);
    k_scan3<<<NBLK, SCAN_B, 0, stream>>>(rowptr, sums);
    k_fill<<<(NEDGE + 255) / 256, 256, 0, stream>>>(ei, flag, dinv, rowptr, fill,
                                                    csr_src, csr_w);
    k_gcn1<<<NGRAPH / 32, 256, 0, stream>>>(rowptr, deg, csr_src, csr_w, dinv,
                                            comb, W1, b1, x1);
    k_agg2<<<NGRAPH / 4, 256, 0, stream>>>(rowptr, deg, csr_src, csr_w, dinv,
                                           x1, agg2);
    k_mlp<<<NGRAPH / TILE, 256, 0, stream>>>(agg2, W2, b2, fc1w, fc1b,
                                             fc2w, fc2b, out);
}

// Round 11
// 501.841 us; speedup vs baseline: 1.3545x; 1.0885x over previous
//
#include <hip/hip_runtime.h>

#define NGRAPH 100000
#define NEDGE  1600000
#define HID    128
#define SCAN_B 512
#define NBLK   ((NGRAPH + SCAN_B - 1) / SCAN_B)   // 196
#define TILE   64                                  // nodes per k_mlp block

__device__ __forceinline__ int e_src(const int* ei, int is64, int e) {
    return is64 ? ei[2 * e] : ei[e];
}
__device__ __forceinline__ int e_dst(const int* ei, int is64, int e) {
    return is64 ? ei[2 * NEDGE + 2 * e] : ei[NEDGE + e];
}

// ---------- combined features + deg/fill init + int64-detect (block 0, wave 0) ----------
__global__ void k_prep(const float* __restrict__ obs, const int* __restrict__ ei,
                       float* __restrict__ comb, int* __restrict__ deg,
                       int* __restrict__ fill, int* __restrict__ flag) {
    if (blockIdx.x == 0 && threadIdx.x < 64) {
        int v = ei[2 * threadIdx.x + 1];           // odd words of src region
        unsigned long long b = __ballot(v != 0);
        if (threadIdx.x == 0) flag[0] = (b == 0ull) ? 1 : 0;  // 1 => int64
    }
    int i = blockIdx.x * blockDim.x + threadIdx.x;
    if (i >= NGRAPH) return;
    int n = i / 20, c = i % 20;
    const float* nf = obs + 3 + n * 4;
    const float* cf = obs + 3 + 20000 + c * 3;
    float* o = comb + i * 7;
    o[0] = nf[0]; o[1] = nf[1]; o[2] = nf[2]; o[3] = nf[3];
    o[4] = cf[0]; o[5] = cf[1]; o[6] = cf[2];
    deg[i] = 0;
    fill[i] = 0;
}

__global__ void k_deg(const int* __restrict__ ei, const int* __restrict__ flag,
                      int* __restrict__ deg) {
    int e = blockIdx.x * blockDim.x + threadIdx.x;
    if (e >= NEDGE) return;
    atomicAdd(&deg[e_dst(ei, flag[0], e)], 1);
}

// ---------- exclusive scan of deg -> rowptr (3-kernel hierarchical); also dinv ----------
__global__ void __launch_bounds__(SCAN_B) k_scan1(const int* __restrict__ deg,
                                                  int* __restrict__ rowptr,
                                                  int* __restrict__ sums,
                                                  float* __restrict__ dinv) {
    __shared__ int sh[SCAN_B];
    int t = threadIdx.x;
    int i = blockIdx.x * SCAN_B + t;
    int val = (i < NGRAPH) ? deg[i] : 0;
    if (i < NGRAPH) dinv[i] = rsqrtf((float)(val + 1));   // +1: self loop
    sh[t] = val;
    __syncthreads();
    for (int o = 1; o < SCAN_B; o <<= 1) {
        int x = (t >= o) ? sh[t - o] : 0;
        __syncthreads();
        sh[t] += x;
        __syncthreads();
    }
    if (i < NGRAPH) rowptr[i] = sh[t] - val;          // exclusive within block
    if (t == SCAN_B - 1) sums[blockIdx.x] = sh[t];    // block total
}

__global__ void __launch_bounds__(256) k_scan2(int* __restrict__ sums) {
    __shared__ int sh[256];
    int t = threadIdx.x;
    int val = (t < NBLK) ? sums[t] : 0;
    sh[t] = val;
    __syncthreads();
    for (int o = 1; o < 256; o <<= 1) {
        int x = (t >= o) ? sh[t - o] : 0;
        __syncthreads();
        sh[t] += x;
        __syncthreads();
    }
    if (t < NBLK) sums[t] = sh[t] - val;              // exclusive block offsets
}

__global__ void __launch_bounds__(SCAN_B) k_scan3(int* __restrict__ rowptr,
                                                  const int* __restrict__ sums) {
    int i = blockIdx.x * SCAN_B + threadIdx.x;
    if (i < NGRAPH) rowptr[i] += sums[blockIdx.x];
}

// ---------- scatter edges into packed CSR slots: int2{src, w-bits} ----------
__global__ void k_fill(const int* __restrict__ ei, const int* __restrict__ flag,
                       const float* __restrict__ dinv,
                       const int* __restrict__ rowptr, int* __restrict__ fill,
                       int2* __restrict__ csr) {
    int e = blockIdx.x * blockDim.x + threadIdx.x;
    if (e >= NEDGE) return;
    int is64 = flag[0];
    int s = e_src(ei, is64, e);
    int d = e_dst(ei, is64, e);
    int pos = rowptr[d] + atomicAdd(&fill[d], 1);
    csr[pos] = make_int2(s, __float_as_int(dinv[s] * dinv[d]));
}

// ---------- fused GCN layer 1: CSR agg (7-dim) + [7->128] matmul + ReLU ----------
__global__ void __launch_bounds__(256) k_gcn1(const int* __restrict__ rowptr,
                                              const int* __restrict__ deg,
                                              const int2* __restrict__ csr,
                                              const float* __restrict__ dinv,
                                              const float* __restrict__ comb,
                                              const float* __restrict__ W1,
                                              const float* __restrict__ b1,
                                              float* __restrict__ x1) {
    __shared__ float agg_s[32][8];
    int g = threadIdx.x >> 3;                  // node within block
    int f = threadIdx.x & 7;
    int d = blockIdx.x * 32 + g;
    if (f < 7) {
        int start = rowptr[d], n = deg[d];
        float acc = 0.0f;
        for (int j = 0; j < n; ++j) {
            int2 ed = csr[start + j];
            acc += __int_as_float(ed.y) * comb[ed.x * 7 + f];
        }
        float dv = dinv[d];
        acc += dv * dv * comb[d * 7 + f];      // self loop
        agg_s[g][f] = acc;
    }
    __syncthreads();
    float a[7];
    #pragma unroll
    for (int q = 0; q < 7; ++q) a[q] = agg_s[g][q];   // LDS broadcast per node
    int h0 = f * 16;
    #pragma unroll
    for (int j = 0; j < 4; ++j) {
        int h = h0 + j * 4;
        float4 acc4 = *reinterpret_cast<const float4*>(b1 + h);
        #pragma unroll
        for (int q = 0; q < 7; ++q) {
            float4 w = *reinterpret_cast<const float4*>(W1 + q * HID + h);
            acc4.x = fmaf(a[q], w.x, acc4.x);
            acc4.y = fmaf(a[q], w.y, acc4.y);
            acc4.z = fmaf(a[q], w.z, acc4.z);
            acc4.w = fmaf(a[q], w.w, acc4.w);
        }
        acc4.x = fmaxf(acc4.x, 0.0f); acc4.y = fmaxf(acc4.y, 0.0f);
        acc4.z = fmaxf(acc4.z, 0.0f); acc4.w = fmaxf(acc4.w, 0.0f);
        *reinterpret_cast<float4*>(x1 + (size_t)d * HID + h) = acc4;
    }
}

// ---------- layer-2 agg over CSR: 1 wave/node, lane holds 2 of 128 feats ----------
// Edge loop unrolled x2: two independent row-gathers in flight per iteration.
__global__ void __launch_bounds__(256) k_agg2(const int* __restrict__ rowptr,
                                              const int* __restrict__ deg,
                                              const int2* __restrict__ csr,
                                              const float* __restrict__ dinv,
                                              const float* __restrict__ x1,
                                              float* __restrict__ agg2) {
    int wave = threadIdx.x >> 6;
    int lane = threadIdx.x & 63;
    int d = blockIdx.x * 4 + wave;
    int f0 = lane * 2;
    int start = rowptr[d], n = deg[d];
    float2 acc = {0.0f, 0.0f};
    int j = 0;
    for (; j + 2 <= n; j += 2) {
        int2 e0 = csr[start + j];
        int2 e1 = csr[start + j + 1];
        float w0 = __int_as_float(e0.y);
        float w1 = __int_as_float(e1.y);
        float2 v0 = *reinterpret_cast<const float2*>(x1 + (size_t)e0.x * HID + f0);
        float2 v1 = *reinterpret_cast<const float2*>(x1 + (size_t)e1.x * HID + f0);
        acc.x += w0 * v0.x + w1 * v1.x;
        acc.y += w0 * v0.y + w1 * v1.y;
    }
    if (j < n) {
        int2 e0 = csr[start + j];
        float w0 = __int_as_float(e0.y);
        float2 v0 = *reinterpret_cast<const float2*>(x1 + (size_t)e0.x * HID + f0);
        acc.x += w0 * v0.x;
        acc.y += w0 * v0.y;
    }
    float dv = dinv[d];
    float ws = dv * dv;
    float2 v = *reinterpret_cast<const float2*>(x1 + (size_t)d * HID + f0);
    acc.x += ws * v.x;
    acc.y += ws * v.y;
    *reinterpret_cast<float2*>(agg2 + (size_t)d * HID + f0) = acc;
}

// ---------- fused dense tail, LDS-resident, 4-node x 8-output register blocking ----
// 256 thr = 16 tx (h0=tx*8) x 16 ty (4 nodes). Per 4-k chunk: 12 ds_read_b128 feed
// 128 MACs (10.7 MAC/read vs 8 in r10) and TILE=64 halves wave count -> per-phase
// LDS reads 3.2M -> 2.4M (r10 diagnosis: LDS-issue-bound at 12 waves/CU).
// LDS = 50.7KB -> 3 blocks/CU = 12 waves/CU (same occupancy as measured 37%).
__device__ __forceinline__ void fmad(float4& acc, float s, const float4 w) {
    acc.x = fmaf(s, w.x, acc.x);
    acc.y = fmaf(s, w.y, acc.y);
    acc.z = fmaf(s, w.z, acc.z);
    acc.w = fmaf(s, w.w, acc.w);
}
__device__ __forceinline__ float4 relu4(float4 v) {
    float4 r;
    r.x = fmaxf(v.x, 0.0f); r.y = fmaxf(v.y, 0.0f);
    r.z = fmaxf(v.z, 0.0f); r.w = fmaxf(v.w, 0.0f);
    return r;
}

__global__ void __launch_bounds__(256, 3) k_mlp(const float* __restrict__ agg2,
                                                const float* __restrict__ W2,
                                                const float* __restrict__ b2,
                                                const float* __restrict__ fc1w,
                                                const float* __restrict__ fc1b,
                                                const float* __restrict__ fc2w,
                                                const float* __restrict__ fc2b,
                                                float* __restrict__ out) {
    __shared__ float as_[TILE][HID + 4];   // activation tile, then x2 tile (33.8KB)
    __shared__ float ws[32][HID + 4];      // 32 staged weight rows (16.9KB)
    const int tid = threadIdx.x;
    const int tx = tid & 15;               // h0 = tx*8
    const int ty = tid >> 4;               // nodes ty*4 .. ty*4+3
    const int n0 = blockIdx.x * TILE;      // tail block: 32 valid nodes, guarded
    const int h0 = tx * 8;

    // stage activations: 64 rows x 128 floats = 2048 f4, 8 per thread (clamped rows)
    #pragma unroll
    for (int q = 0; q < 8; ++q) {
        int idx = (q * 256 + tid) * 4;
        int row = idx >> 7, col = idx & 127;
        int nr = n0 + row; if (nr >= NGRAPH) nr = NGRAPH - 1;
        *reinterpret_cast<float4*>(&as_[row][col]) =
            *reinterpret_cast<const float4*>(agg2 + (size_t)nr * HID + col);
    }

    // ---- phase A: x2 = relu(agg2 @ W2 + b2) ----
    float4 cA[4], cB[4];
    {
        float4 bA = *reinterpret_cast<const float4*>(b2 + h0);
        float4 bB = *reinterpret_cast<const float4*>(b2 + h0 + 4);
        #pragma unroll
        for (int r = 0; r < 4; ++r) { cA[r] = bA; cB[r] = bB; }
    }
    for (int ks = 0; ks < HID; ks += 32) {
        #pragma unroll
        for (int q = 0; q < 4; ++q) {
            int idx = (q * 256 + tid) * 4;
            int row = idx >> 7, col = idx & 127;
            *reinterpret_cast<float4*>(&ws[row][col]) =
                *reinterpret_cast<const float4*>(W2 + (size_t)(ks + row) * HID + col);
        }
        __syncthreads();                    // also covers as_ staging on ks==0
        #pragma unroll
        for (int k = 0; k < 32; k += 4) {
            float4 wA0 = *reinterpret_cast<const float4*>(&ws[k + 0][h0]);
            float4 wB0 = *reinterpret_cast<const float4*>(&ws[k + 0][h0 + 4]);
            float4 wA1 = *reinterpret_cast<const float4*>(&ws[k + 1][h0]);
            float4 wB1 = *reinterpret_cast<const float4*>(&ws[k + 1][h0 + 4]);
            float4 wA2 = *reinterpret_cast<const float4*>(&ws[k + 2][h0]);
            float4 wB2 = *reinterpret_cast<const float4*>(&ws[k + 2][h0 + 4]);
            float4 wA3 = *reinterpret_cast<const float4*>(&ws[k + 3][h0]);
            float4 wB3 = *reinterpret_cast<const float4*>(&ws[k + 3][h0 + 4]);
            #pragma unroll
            for (int r = 0; r < 4; ++r) {
                float4 a = *reinterpret_cast<const float4*>(&as_[ty * 4 + r][ks + k]);
                fmad(cA[r], a.x, wA0); fmad(cB[r], a.x, wB0);
                fmad(cA[r], a.y, wA1); fmad(cB[r], a.y, wB1);
                fmad(cA[r], a.z, wA2); fmad(cB[r], a.z, wB2);
                fmad(cA[r], a.w, wA3); fmad(cB[r], a.w, wB3);
            }
        }
        __syncthreads();                    // protect ws for next stage
    }
    // write x2 into as_ (all phase-A reads completed at the trailing sync)
    #pragma unroll
    for (int r = 0; r < 4; ++r) {
        *reinterpret_cast<float4*>(&as_[ty * 4 + r][h0])     = relu4(cA[r]);
        *reinterpret_cast<float4*>(&as_[ty * 4 + r][h0 + 4]) = relu4(cB[r]);
    }

    // ---- phase B: x3 = relu(x2 @ fc1w + fc1b) ----
    float4 dA[4], dB[4];
    {
        float4 bA = *reinterpret_cast<const float4*>(fc1b + h0);
        float4 bB = *reinterpret_cast<const float4*>(fc1b + h0 + 4);
        #pragma unroll
        for (int r = 0; r < 4; ++r) { dA[r] = bA; dB[r] = bB; }
    }
    for (int ks = 0; ks < HID; ks += 32) {
        #pragma unroll
        for (int q = 0; q < 4; ++q) {
            int idx = (q * 256 + tid) * 4;
            int row = idx >> 7, col = idx & 127;
            *reinterpret_cast<float4*>(&ws[row][col]) =
                *reinterpret_cast<const float4*>(fc1w + (size_t)(ks + row) * HID + col);
        }
        __syncthreads();                    // also makes x2 writes visible (ks==0)
        #pragma unroll
        for (int k = 0; k < 32; k += 4) {
            float4 wA0 = *reinterpret_cast<const float4*>(&ws[k + 0][h0]);
            float4 wB0 = *reinterpret_cast<const float4*>(&ws[k + 0][h0 + 4]);
            float4 wA1 = *reinterpret_cast<const float4*>(&ws[k + 1][h0]);
            float4 wB1 = *reinterpret_cast<const float4*>(&ws[k + 1][h0 + 4]);
            float4 wA2 = *reinterpret_cast<const float4*>(&ws[k + 2][h0]);
            float4 wB2 = *reinterpret_cast<const float4*>(&ws[k + 2][h0 + 4]);
            float4 wA3 = *reinterpret_cast<const float4*>(&ws[k + 3][h0]);
            float4 wB3 = *reinterpret_cast<const float4*>(&ws[k + 3][h0 + 4]);
            #pragma unroll
            for (int r = 0; r < 4; ++r) {
                float4 a = *reinterpret_cast<const float4*>(&as_[ty * 4 + r][ks + k]);
                fmad(dA[r], a.x, wA0); fmad(dB[r], a.x, wB0);
                fmad(dA[r], a.y, wA1); fmad(dB[r], a.y, wB1);
                fmad(dA[r], a.z, wA2); fmad(dB[r], a.z, wB2);
                fmad(dA[r], a.w, wA3); fmad(dB[r], a.w, wB3);
            }
        }
        __syncthreads();
    }

    // ---- phase C: out = x3 @ fc2w + fc2b (reduce over 16 tx lanes) ----
    float4 wqA = *reinterpret_cast<const float4*>(fc2w + h0);
    float4 wqB = *reinterpret_cast<const float4*>(fc2w + h0 + 4);
    float p[4];
    #pragma unroll
    for (int r = 0; r < 4; ++r) {
        float4 rA = relu4(dA[r]);
        float4 rB = relu4(dB[r]);
        p[r] = rA.x * wqA.x + rA.y * wqA.y + rA.z * wqA.z + rA.w * wqA.w
             + rB.x * wqB.x + rB.y * wqB.y + rB.z * wqB.z + rB.w * wqB.w;
    }
    #pragma unroll
    for (int m = 1; m < 16; m <<= 1) {     // xor-mask < 16 stays within the tx group
        #pragma unroll
        for (int r = 0; r < 4; ++r) p[r] += __shfl_xor(p[r], m);
    }
    if (tx == 0) {
        float bq = fc2b[0];
        int nb = n0 + ty * 4;
        #pragma unroll
        for (int r = 0; r < 4; ++r)
            if (nb + r < NGRAPH) out[nb + r] = p[r] + bq;
    }
}

extern "C" void kernel_launch(void* const* d_in, const int* in_sizes, int n_in,
                              void* d_out, int out_size, void* d_ws, size_t ws_size,
                              hipStream_t stream) {
    const float* obs  = (const float*)d_in[0];
    const int*   ei   = (const int*)d_in[1];
    const float* W1   = (const float*)d_in[2];
    const float* b1   = (const float*)d_in[3];
    const float* W2   = (const float*)d_in[4];
    const float* b2   = (const float*)d_in[5];
    const float* fc1w = (const float*)d_in[6];
    const float* fc1b = (const float*)d_in[7];
    const float* fc2w = (const float*)d_in[8];
    const float* fc2b = (const float*)d_in[9];
    float* out = (float*)d_out;

    char* base = (char*)d_ws;
    size_t off = 0;
    auto take = [&](size_t bytes) {
        char* p = base + off;
        off += (bytes + 255) & ~(size_t)255;
        return p;
    };
    int*   deg     = (int*)take((size_t)NGRAPH * 4);
    int*   rowptr  = (int*)take((size_t)NGRAPH * 4);
    int*   fill    = (int*)take((size_t)NGRAPH * 4);
    int*   sums    = (int*)take((size_t)NBLK * 4);
    float* dinv    = (float*)take((size_t)NGRAPH * 4);
    int2*  csr     = (int2*)take((size_t)NEDGE * 8);
    float* comb    = (float*)take((size_t)NGRAPH * 7 * 4);
    float* x1      = (float*)take((size_t)NGRAPH * HID * 4);
    float* agg2    = (float*)take((size_t)NGRAPH * HID * 4);
    int*   flag    = (int*)take(256);

    k_prep<<<(NGRAPH + 255) / 256, 256, 0, stream>>>(obs, ei, comb, deg, fill, flag);
    k_deg<<<(NEDGE + 255) / 256, 256, 0, stream>>>(ei, flag, deg);
    k_scan1<<<NBLK, SCAN_B, 0, stream>>>(deg, rowptr, sums, dinv);
    k_scan2<<<1, 256, 0, stream>>>(sums);
    k_scan3<<<NBLK, SCAN_B, 0, stream>>>(rowptr, sums);
    k_fill<<<(NEDGE + 255) / 256, 256, 0, stream>>>(ei, flag, dinv, rowptr, fill, csr);
    k_gcn1<<<NGRAPH / 32, 256, 0, stream>>>(rowptr, deg, csr, dinv,
                                            comb, W1, b1, x1);
    k_agg2<<<NGRAPH / 4, 256, 0, stream>>>(rowptr, deg, csr, dinv, x1, agg2);
    k_mlp<<<(NGRAPH + TILE - 1) / TILE, 256, 0, stream>>>(agg2, W2, b2,
                                                          fc1w, fc1b,
                                                          fc2w, fc2b, out);
}

// Round 12
// 466.959 us; speedup vs baseline: 1.4557x; 1.0747x over previous
//
#include <hip/hip_runtime.h>
#include <hip/hip_fp16.h>

#define NGRAPH 100000
#define NEDGE  1600000
#define HID    128
#define SCAN_B 512
#define NBLK   ((NGRAPH + SCAN_B - 1) / SCAN_B)   // 196
#define TILE   64                                  // nodes per k_mlp block

__device__ __forceinline__ int e_src(const int* ei, int is64, int e) {
    return is64 ? ei[2 * e] : ei[e];
}
__device__ __forceinline__ int e_dst(const int* ei, int is64, int e) {
    return is64 ? ei[2 * NEDGE + 2 * e] : ei[NEDGE + e];
}

// ---------- combined features + deg/fill init + int64-detect (block 0, wave 0) ----------
__global__ void k_prep(const float* __restrict__ obs, const int* __restrict__ ei,
                       float* __restrict__ comb, int* __restrict__ deg,
                       int* __restrict__ fill, int* __restrict__ flag) {
    if (blockIdx.x == 0 && threadIdx.x < 64) {
        int v = ei[2 * threadIdx.x + 1];           // odd words of src region
        unsigned long long b = __ballot(v != 0);
        if (threadIdx.x == 0) flag[0] = (b == 0ull) ? 1 : 0;  // 1 => int64
    }
    int i = blockIdx.x * blockDim.x + threadIdx.x;
    if (i >= NGRAPH) return;
    int n = i / 20, c = i % 20;
    const float* nf = obs + 3 + n * 4;
    const float* cf = obs + 3 + 20000 + c * 3;
    float* o = comb + i * 7;
    o[0] = nf[0]; o[1] = nf[1]; o[2] = nf[2]; o[3] = nf[3];
    o[4] = cf[0]; o[5] = cf[1]; o[6] = cf[2];
    deg[i] = 0;
    fill[i] = 0;
}

__global__ void k_deg(const int* __restrict__ ei, const int* __restrict__ flag,
                      int* __restrict__ deg) {
    int e = blockIdx.x * blockDim.x + threadIdx.x;
    if (e >= NEDGE) return;
    atomicAdd(&deg[e_dst(ei, flag[0], e)], 1);
}

// ---------- exclusive scan of deg -> rowptr (3-kernel hierarchical); also dinv ----------
__global__ void __launch_bounds__(SCAN_B) k_scan1(const int* __restrict__ deg,
                                                  int* __restrict__ rowptr,
                                                  int* __restrict__ sums,
                                                  float* __restrict__ dinv) {
    __shared__ int sh[SCAN_B];
    int t = threadIdx.x;
    int i = blockIdx.x * SCAN_B + t;
    int val = (i < NGRAPH) ? deg[i] : 0;
    if (i < NGRAPH) dinv[i] = rsqrtf((float)(val + 1));   // +1: self loop
    sh[t] = val;
    __syncthreads();
    for (int o = 1; o < SCAN_B; o <<= 1) {
        int x = (t >= o) ? sh[t - o] : 0;
        __syncthreads();
        sh[t] += x;
        __syncthreads();
    }
    if (i < NGRAPH) rowptr[i] = sh[t] - val;          // exclusive within block
    if (t == SCAN_B - 1) sums[blockIdx.x] = sh[t];    // block total
}

__global__ void __launch_bounds__(256) k_scan2(int* __restrict__ sums) {
    __shared__ int sh[256];
    int t = threadIdx.x;
    int val = (t < NBLK) ? sums[t] : 0;
    sh[t] = val;
    __syncthreads();
    for (int o = 1; o < 256; o <<= 1) {
        int x = (t >= o) ? sh[t - o] : 0;
        __syncthreads();
        sh[t] += x;
        __syncthreads();
    }
    if (t < NBLK) sums[t] = sh[t] - val;              // exclusive block offsets
}

__global__ void __launch_bounds__(SCAN_B) k_scan3(int* __restrict__ rowptr,
                                                  const int* __restrict__ sums) {
    int i = blockIdx.x * SCAN_B + threadIdx.x;
    if (i < NGRAPH) rowptr[i] += sums[blockIdx.x];
}

// ---------- scatter edges into packed CSR slots: int2{src, w-bits} ----------
__global__ void k_fill(const int* __restrict__ ei, const int* __restrict__ flag,
                       const float* __restrict__ dinv,
                       const int* __restrict__ rowptr, int* __restrict__ fill,
                       int2* __restrict__ csr) {
    int e = blockIdx.x * blockDim.x + threadIdx.x;
    if (e >= NEDGE) return;
    int is64 = flag[0];
    int s = e_src(ei, is64, e);
    int d = e_dst(ei, is64, e);
    int pos = rowptr[d] + atomicAdd(&fill[d], 1);
    csr[pos] = make_int2(s, __float_as_int(dinv[s] * dinv[d]));
}

// ---------- fused GCN layer 1: CSR agg (7-dim) + [7->128] matmul + ReLU -> fp16 x1 ----
__global__ void __launch_bounds__(256) k_gcn1(const int* __restrict__ rowptr,
                                              const int* __restrict__ deg,
                                              const int2* __restrict__ csr,
                                              const float* __restrict__ dinv,
                                              const float* __restrict__ comb,
                                              const float* __restrict__ W1,
                                              const float* __restrict__ b1,
                                              __half* __restrict__ x1) {
    __shared__ float agg_s[32][8];
    int g = threadIdx.x >> 3;                  // node within block
    int f = threadIdx.x & 7;
    int d = blockIdx.x * 32 + g;
    if (f < 7) {
        int start = rowptr[d], n = deg[d];
        float acc = 0.0f;
        for (int j = 0; j < n; ++j) {
            int2 ed = csr[start + j];
            acc += __int_as_float(ed.y) * comb[ed.x * 7 + f];
        }
        float dv = dinv[d];
        acc += dv * dv * comb[d * 7 + f];      // self loop
        agg_s[g][f] = acc;
    }
    __syncthreads();
    float a[7];
    #pragma unroll
    for (int q = 0; q < 7; ++q) a[q] = agg_s[g][q];   // LDS broadcast per node
    int h0 = f * 16;
    #pragma unroll
    for (int j = 0; j < 4; ++j) {
        int h = h0 + j * 4;
        float4 acc4 = *reinterpret_cast<const float4*>(b1 + h);
        #pragma unroll
        for (int q = 0; q < 7; ++q) {
            float4 w = *reinterpret_cast<const float4*>(W1 + q * HID + h);
            acc4.x = fmaf(a[q], w.x, acc4.x);
            acc4.y = fmaf(a[q], w.y, acc4.y);
            acc4.z = fmaf(a[q], w.z, acc4.z);
            acc4.w = fmaf(a[q], w.w, acc4.w);
        }
        __half2 h01 = __floats2half2_rn(fmaxf(acc4.x, 0.0f), fmaxf(acc4.y, 0.0f));
        __half2 h23 = __floats2half2_rn(fmaxf(acc4.z, 0.0f), fmaxf(acc4.w, 0.0f));
        uint2 pk;
        pk.x = *reinterpret_cast<unsigned int*>(&h01);
        pk.y = *reinterpret_cast<unsigned int*>(&h23);
        *reinterpret_cast<uint2*>(x1 + (size_t)d * HID + h) = pk;   // 8B aligned
    }
}

// ---------- layer-2 agg over CSR: 1 wave/node, lane holds 2 of 128 feats (fp16 x1) ----
// Row = 64 lanes x half2 = 256B coalesced (was 512B fp32): r11 counters showed
// k_agg2 gather-BW-bound (FETCH 407MB @ 46% HBM peak) -> halve bytes/row.
__global__ void __launch_bounds__(256) k_agg2(const int* __restrict__ rowptr,
                                              const int* __restrict__ deg,
                                              const int2* __restrict__ csr,
                                              const float* __restrict__ dinv,
                                              const __half2* __restrict__ x1,
                                              float* __restrict__ agg2) {
    int wave = threadIdx.x >> 6;
    int lane = threadIdx.x & 63;
    int d = blockIdx.x * 4 + wave;
    int f0 = lane * 2;
    int start = rowptr[d], n = deg[d];
    float2 acc = {0.0f, 0.0f};
    int j = 0;
    for (; j + 2 <= n; j += 2) {
        int2 e0 = csr[start + j];
        int2 e1 = csr[start + j + 1];
        float w0 = __int_as_float(e0.y);
        float w1 = __int_as_float(e1.y);
        float2 v0 = __half22float2(x1[(size_t)e0.x * 64 + lane]);
        float2 v1 = __half22float2(x1[(size_t)e1.x * 64 + lane]);
        acc.x = fmaf(w0, v0.x, acc.x);
        acc.y = fmaf(w0, v0.y, acc.y);
        acc.x = fmaf(w1, v1.x, acc.x);
        acc.y = fmaf(w1, v1.y, acc.y);
    }
    if (j < n) {
        int2 e0 = csr[start + j];
        float w0 = __int_as_float(e0.y);
        float2 v0 = __half22float2(x1[(size_t)e0.x * 64 + lane]);
        acc.x = fmaf(w0, v0.x, acc.x);
        acc.y = fmaf(w0, v0.y, acc.y);
    }
    float dv = dinv[d];
    float ws = dv * dv;
    float2 v = __half22float2(x1[(size_t)d * 64 + lane]);
    acc.x = fmaf(ws, v.x, acc.x);
    acc.y = fmaf(ws, v.y, acc.y);
    *reinterpret_cast<float2*>(agg2 + (size_t)d * HID + f0) = acc;
}

// ---------- fused dense tail, LDS-resident, 4-node x 8-output register blocking ----
__device__ __forceinline__ void fmad(float4& acc, float s, const float4 w) {
    acc.x = fmaf(s, w.x, acc.x);
    acc.y = fmaf(s, w.y, acc.y);
    acc.z = fmaf(s, w.z, acc.z);
    acc.w = fmaf(s, w.w, acc.w);
}
__device__ __forceinline__ float4 relu4(float4 v) {
    float4 r;
    r.x = fmaxf(v.x, 0.0f); r.y = fmaxf(v.y, 0.0f);
    r.z = fmaxf(v.z, 0.0f); r.w = fmaxf(v.w, 0.0f);
    return r;
}

__global__ void __launch_bounds__(256, 3) k_mlp(const float* __restrict__ agg2,
                                                const float* __restrict__ W2,
                                                const float* __restrict__ b2,
                                                const float* __restrict__ fc1w,
                                                const float* __restrict__ fc1b,
                                                const float* __restrict__ fc2w,
                                                const float* __restrict__ fc2b,
                                                float* __restrict__ out) {
    __shared__ float as_[TILE][HID + 4];   // activation tile, then x2 tile (33.8KB)
    __shared__ float ws[32][HID + 4];      // 32 staged weight rows (16.9KB)
    const int tid = threadIdx.x;
    const int tx = tid & 15;               // h0 = tx*8
    const int ty = tid >> 4;               // nodes ty*4 .. ty*4+3
    const int n0 = blockIdx.x * TILE;      // tail block: 32 valid nodes, guarded
    const int h0 = tx * 8;

    // stage activations: 64 rows x 128 floats = 2048 f4, 8 per thread (clamped rows)
    #pragma unroll
    for (int q = 0; q < 8; ++q) {
        int idx = (q * 256 + tid) * 4;
        int row = idx >> 7, col = idx & 127;
        int nr = n0 + row; if (nr >= NGRAPH) nr = NGRAPH - 1;
        *reinterpret_cast<float4*>(&as_[row][col]) =
            *reinterpret_cast<const float4*>(agg2 + (size_t)nr * HID + col);
    }

    // ---- phase A: x2 = relu(agg2 @ W2 + b2) ----
    float4 cA[4], cB[4];
    {
        float4 bA = *reinterpret_cast<const float4*>(b2 + h0);
        float4 bB = *reinterpret_cast<const float4*>(b2 + h0 + 4);
        #pragma unroll
        for (int r = 0; r < 4; ++r) { cA[r] = bA; cB[r] = bB; }
    }
    for (int ks = 0; ks < HID; ks += 32) {
        #pragma unroll
        for (int q = 0; q < 4; ++q) {
            int idx = (q * 256 + tid) * 4;
            int row = idx >> 7, col = idx & 127;
            *reinterpret_cast<float4*>(&ws[row][col]) =
                *reinterpret_cast<const float4*>(W2 + (size_t)(ks + row) * HID + col);
        }
        __syncthreads();                    // also covers as_ staging on ks==0
        #pragma unroll
        for (int k = 0; k < 32; k += 4) {
            float4 wA0 = *reinterpret_cast<const float4*>(&ws[k + 0][h0]);
            float4 wB0 = *reinterpret_cast<const float4*>(&ws[k + 0][h0 + 4]);
            float4 wA1 = *reinterpret_cast<const float4*>(&ws[k + 1][h0]);
            float4 wB1 = *reinterpret_cast<const float4*>(&ws[k + 1][h0 + 4]);
            float4 wA2 = *reinterpret_cast<const float4*>(&ws[k + 2][h0]);
            float4 wB2 = *reinterpret_cast<const float4*>(&ws[k + 2][h0 + 4]);
            float4 wA3 = *reinterpret_cast<const float4*>(&ws[k + 3][h0]);
            float4 wB3 = *reinterpret_cast<const float4*>(&ws[k + 3][h0 + 4]);
            #pragma unroll
            for (int r = 0; r < 4; ++r) {
                float4 a = *reinterpret_cast<const float4*>(&as_[ty * 4 + r][ks + k]);
                fmad(cA[r], a.x, wA0); fmad(cB[r], a.x, wB0);
                fmad(cA[r], a.y, wA1); fmad(cB[r], a.y, wB1);
                fmad(cA[r], a.z, wA2); fmad(cB[r], a.z, wB2);
                fmad(cA[r], a.w, wA3); fmad(cB[r], a.w, wB3);
            }
        }
        __syncthreads();                    // protect ws for next stage
    }
    // write x2 into as_ (all phase-A reads completed at the trailing sync)
    #pragma unroll
    for (int r = 0; r < 4; ++r) {
        *reinterpret_cast<float4*>(&as_[ty * 4 + r][h0])     = relu4(cA[r]);
        *reinterpret_cast<float4*>(&as_[ty * 4 + r][h0 + 4]) = relu4(cB[r]);
    }

    // ---- phase B: x3 = relu(x2 @ fc1w + fc1b) ----
    float4 dA[4], dB[4];
    {
        float4 bA = *reinterpret_cast<const float4*>(fc1b + h0);
        float4 bB = *reinterpret_cast<const float4*>(fc1b + h0 + 4);
        #pragma unroll
        for (int r = 0; r < 4; ++r) { dA[r] = bA; dB[r] = bB; }
    }
    for (int ks = 0; ks < HID; ks += 32) {
        #pragma unroll
        for (int q = 0; q < 4; ++q) {
            int idx = (q * 256 + tid) * 4;
            int row = idx >> 7, col = idx & 127;
            *reinterpret_cast<float4*>(&ws[row][col]) =
                *reinterpret_cast<const float4*>(fc1w + (size_t)(ks + row) * HID + col);
        }
        __syncthreads();                    // also makes x2 writes visible (ks==0)
        #pragma unroll
        for (int k = 0; k < 32; k += 4) {
            float4 wA0 = *reinterpret_cast<const float4*>(&ws[k + 0][h0]);
            float4 wB0 = *reinterpret_cast<const float4*>(&ws[k + 0][h0 + 4]);
            float4 wA1 = *reinterpret_cast<const float4*>(&ws[k + 1][h0]);
            float4 wB1 = *reinterpret_cast<const float4*>(&ws[k + 1][h0 + 4]);
            float4 wA2 = *reinterpret_cast<const float4*>(&ws[k + 2][h0]);
            float4 wB2 = *reinterpret_cast<const float4*>(&ws[k + 2][h0 + 4]);
            float4 wA3 = *reinterpret_cast<const float4*>(&ws[k + 3][h0]);
            float4 wB3 = *reinterpret_cast<const float4*>(&ws[k + 3][h0 + 4]);
            #pragma unroll
            for (int r = 0; r < 4; ++r) {
                float4 a = *reinterpret_cast<const float4*>(&as_[ty * 4 + r][ks + k]);
                fmad(dA[r], a.x, wA0); fmad(dB[r], a.x, wB0);
                fmad(dA[r], a.y, wA1); fmad(dB[r], a.y, wB1);
                fmad(dA[r], a.z, wA2); fmad(dB[r], a.z, wB2);
                fmad(dA[r], a.w, wA3); fmad(dB[r], a.w, wB3);
            }
        }
        __syncthreads();
    }

    // ---- phase C: out = x3 @ fc2w + fc2b (reduce over 16 tx lanes) ----
    float4 wqA = *reinterpret_cast<const float4*>(fc2w + h0);
    float4 wqB = *reinterpret_cast<const float4*>(fc2w + h0 + 4);
    float p[4];
    #pragma unroll
    for (int r = 0; r < 4; ++r) {
        float4 rA = relu4(dA[r]);
        float4 rB = relu4(dB[r]);
        p[r] = rA.x * wqA.x + rA.y * wqA.y + rA.z * wqA.z + rA.w * wqA.w
             + rB.x * wqB.x + rB.y * wqB.y + rB.z * wqB.z + rB.w * wqB.w;
    }
    #pragma unroll
    for (int m = 1; m < 16; m <<= 1) {     // xor-mask < 16 stays within the tx group
        #pragma unroll
        for (int r = 0; r < 4; ++r) p[r] += __shfl_xor(p[r], m);
    }
    if (tx == 0) {
        float bq = fc2b[0];
        int nb = n0 + ty * 4;
        #pragma unroll
        for (int r = 0; r < 4; ++r)
            if (nb + r < NGRAPH) out[nb + r] = p[r] + bq;
    }
}

extern "C" void kernel_launch(void* const* d_in, const int* in_sizes, int n_in,
                              void* d_out, int out_size, void* d_ws, size_t ws_size,
                              hipStream_t stream) {
    const float* obs  = (const float*)d_in[0];
    const int*   ei   = (const int*)d_in[1];
    const float* W1   = (const float*)d_in[2];
    const float* b1   = (const float*)d_in[3];
    const float* W2   = (const float*)d_in[4];
    const float* b2   = (const float*)d_in[5];
    const float* fc1w = (const float*)d_in[6];
    const float* fc1b = (const float*)d_in[7];
    const float* fc2w = (const float*)d_in[8];
    const float* fc2b = (const float*)d_in[9];
    float* out = (float*)d_out;

    char* base = (char*)d_ws;
    size_t off = 0;
    auto take = [&](size_t bytes) {
        char* p = base + off;
        off += (bytes + 255) & ~(size_t)255;
        return p;
    };
    int*    deg     = (int*)take((size_t)NGRAPH * 4);
    int*    rowptr  = (int*)take((size_t)NGRAPH * 4);
    int*    fill    = (int*)take((size_t)NGRAPH * 4);
    int*    sums    = (int*)take((size_t)NBLK * 4);
    float*  dinv    = (float*)take((size_t)NGRAPH * 4);
    int2*   csr     = (int2*)take((size_t)NEDGE * 8);
    float*  comb    = (float*)take((size_t)NGRAPH * 7 * 4);
    __half* x1      = (__half*)take((size_t)NGRAPH * HID * 2);
    float*  agg2    = (float*)take((size_t)NGRAPH * HID * 4);
    int*    flag    = (int*)take(256);

    k_prep<<<(NGRAPH + 255) / 256, 256, 0, stream>>>(obs, ei, comb, deg, fill, flag);
    k_deg<<<(NEDGE + 255) / 256, 256, 0, stream>>>(ei, flag, deg);
    k_scan1<<<NBLK, SCAN_B, 0, stream>>>(deg, rowptr, sums, dinv);
    k_scan2<<<1, 256, 0, stream>>>(sums);
    k_scan3<<<NBLK, SCAN_B, 0, stream>>>(rowptr, sums);
    k_fill<<<(NEDGE + 255) / 256, 256, 0, stream>>>(ei, flag, dinv, rowptr, fill, csr);
    k_gcn1<<<NGRAPH / 32, 256, 0, stream>>>(rowptr, deg, csr, dinv,
                                            comb, W1, b1, x1);
    k_agg2<<<NGRAPH / 4, 256, 0, stream>>>(rowptr, deg, csr, dinv,
                                           (const __half2*)x1, agg2);
    k_mlp<<<(NGRAPH + TILE - 1) / TILE, 256, 0, stream>>>(agg2, W2, b2,
                                                          fc1w, fc1b,
                                                          fc2w, fc2b, out);
}

// Round 13
// 460.826 us; speedup vs baseline: 1.4751x; 1.0133x over previous
//
#include <hip/hip_runtime.h>
#include <hip/hip_fp16.h>

#define NGRAPH 100000
#define NEDGE  1600000
#define HID    128
#define SCAN_B 512
#define NBLK   ((NGRAPH + SCAN_B - 1) / SCAN_B)   // 196
#define TILE   64                                  // nodes per k_mlp block

__device__ __forceinline__ int e_src(const int* ei, int is64, int e) {
    return is64 ? ei[2 * e] : ei[e];
}
__device__ __forceinline__ int e_dst(const int* ei, int is64, int e) {
    return is64 ? ei[2 * NEDGE + 2 * e] : ei[NEDGE + e];
}

// ---------- combined features + deg/fill init + int64-detect (block 0, wave 0) ----------
__global__ void k_prep(const float* __restrict__ obs, const int* __restrict__ ei,
                       float* __restrict__ comb, int* __restrict__ deg,
                       int* __restrict__ fill, int* __restrict__ flag) {
    if (blockIdx.x == 0 && threadIdx.x < 64) {
        int v = ei[2 * threadIdx.x + 1];           // odd words of src region
        unsigned long long b = __ballot(v != 0);
        if (threadIdx.x == 0) flag[0] = (b == 0ull) ? 1 : 0;  // 1 => int64
    }
    int i = blockIdx.x * blockDim.x + threadIdx.x;
    if (i >= NGRAPH) return;
    int n = i / 20, c = i % 20;
    const float* nf = obs + 3 + n * 4;
    const float* cf = obs + 3 + 20000 + c * 3;
    float* o = comb + i * 7;
    o[0] = nf[0]; o[1] = nf[1]; o[2] = nf[2]; o[3] = nf[3];
    o[4] = cf[0]; o[5] = cf[1]; o[6] = cf[2];
    deg[i] = 0;
    fill[i] = 0;
}

__global__ void k_deg(const int* __restrict__ ei, const int* __restrict__ flag,
                      int* __restrict__ deg) {
    int e = blockIdx.x * blockDim.x + threadIdx.x;
    if (e >= NEDGE) return;
    atomicAdd(&deg[e_dst(ei, flag[0], e)], 1);
}

// ---------- exclusive scan of deg -> rowptr (3-kernel hierarchical); also dinv ----------
__global__ void __launch_bounds__(SCAN_B) k_scan1(const int* __restrict__ deg,
                                                  int* __restrict__ rowptr,
                                                  int* __restrict__ sums,
                                                  float* __restrict__ dinv) {
    __shared__ int sh[SCAN_B];
    int t = threadIdx.x;
    int i = blockIdx.x * SCAN_B + t;
    int val = (i < NGRAPH) ? deg[i] : 0;
    if (i < NGRAPH) dinv[i] = rsqrtf((float)(val + 1));   // +1: self loop
    sh[t] = val;
    __syncthreads();
    for (int o = 1; o < SCAN_B; o <<= 1) {
        int x = (t >= o) ? sh[t - o] : 0;
        __syncthreads();
        sh[t] += x;
        __syncthreads();
    }
    if (i < NGRAPH) rowptr[i] = sh[t] - val;          // exclusive within block
    if (t == SCAN_B - 1) sums[blockIdx.x] = sh[t];    // block total
}

__global__ void __launch_bounds__(256) k_scan2(int* __restrict__ sums) {
    __shared__ int sh[256];
    int t = threadIdx.x;
    int val = (t < NBLK) ? sums[t] : 0;
    sh[t] = val;
    __syncthreads();
    for (int o = 1; o < 256; o <<= 1) {
        int x = (t >= o) ? sh[t - o] : 0;
        __syncthreads();
        sh[t] += x;
        __syncthreads();
    }
    if (t < NBLK) sums[t] = sh[t] - val;              // exclusive block offsets
}

__global__ void __launch_bounds__(SCAN_B) k_scan3(int* __restrict__ rowptr,
                                                  const int* __restrict__ sums) {
    int i = blockIdx.x * SCAN_B + threadIdx.x;
    if (i < NGRAPH) rowptr[i] += sums[blockIdx.x];
}

// ---------- scatter edges into packed CSR slots: int2{src, w-bits} ----------
__global__ void k_fill(const int* __restrict__ ei, const int* __restrict__ flag,
                       const float* __restrict__ dinv,
                       const int* __restrict__ rowptr, int* __restrict__ fill,
                       int2* __restrict__ csr) {
    int e = blockIdx.x * blockDim.x + threadIdx.x;
    if (e >= NEDGE) return;
    int is64 = flag[0];
    int s = e_src(ei, is64, e);
    int d = e_dst(ei, is64, e);
    int pos = rowptr[d] + atomicAdd(&fill[d], 1);
    csr[pos] = make_int2(s, __float_as_int(dinv[s] * dinv[d]));
}

// ---------- fused GCN layer 1: CSR agg (7-dim) + [7->128] matmul + ReLU -> fp16 x1 ----
__global__ void __launch_bounds__(256) k_gcn1(const int* __restrict__ rowptr,
                                              const int* __restrict__ deg,
                                              const int2* __restrict__ csr,
                                              const float* __restrict__ dinv,
                                              const float* __restrict__ comb,
                                              const float* __restrict__ W1,
                                              const float* __restrict__ b1,
                                              __half* __restrict__ x1) {
    __shared__ float agg_s[32][8];
    int g = threadIdx.x >> 3;                  // node within block
    int f = threadIdx.x & 7;
    int d = blockIdx.x * 32 + g;
    if (f < 7) {
        int start = rowptr[d], n = deg[d];
        float acc = 0.0f;
        for (int j = 0; j < n; ++j) {
            int2 ed = csr[start + j];
            acc += __int_as_float(ed.y) * comb[ed.x * 7 + f];
        }
        float dv = dinv[d];
        acc += dv * dv * comb[d * 7 + f];      // self loop
        agg_s[g][f] = acc;
    }
    __syncthreads();
    float a[7];
    #pragma unroll
    for (int q = 0; q < 7; ++q) a[q] = agg_s[g][q];   // LDS broadcast per node
    int h0 = f * 16;
    #pragma unroll
    for (int j = 0; j < 4; ++j) {
        int h = h0 + j * 4;
        float4 acc4 = *reinterpret_cast<const float4*>(b1 + h);
        #pragma unroll
        for (int q = 0; q < 7; ++q) {
            float4 w = *reinterpret_cast<const float4*>(W1 + q * HID + h);
            acc4.x = fmaf(a[q], w.x, acc4.x);
            acc4.y = fmaf(a[q], w.y, acc4.y);
            acc4.z = fmaf(a[q], w.z, acc4.z);
            acc4.w = fmaf(a[q], w.w, acc4.w);
        }
        __half2 h01 = __floats2half2_rn(fmaxf(acc4.x, 0.0f), fmaxf(acc4.y, 0.0f));
        __half2 h23 = __floats2half2_rn(fmaxf(acc4.z, 0.0f), fmaxf(acc4.w, 0.0f));
        uint2 pk;
        pk.x = *reinterpret_cast<unsigned int*>(&h01);
        pk.y = *reinterpret_cast<unsigned int*>(&h23);
        *reinterpret_cast<uint2*>(x1 + (size_t)d * HID + h) = pk;   // 8B aligned
    }
}

// ---------- layer-2 agg over CSR: 1 wave/node, lane holds 2 of 128 feats (fp16 x1) ----
__global__ void __launch_bounds__(256) k_agg2(const int* __restrict__ rowptr,
                                              const int* __restrict__ deg,
                                              const int2* __restrict__ csr,
                                              const float* __restrict__ dinv,
                                              const __half2* __restrict__ x1,
                                              float* __restrict__ agg2) {
    int wave = threadIdx.x >> 6;
    int lane = threadIdx.x & 63;
    int d = blockIdx.x * 4 + wave;
    int f0 = lane * 2;
    int start = rowptr[d], n = deg[d];
    float2 acc = {0.0f, 0.0f};
    int j = 0;
    for (; j + 2 <= n; j += 2) {
        int2 e0 = csr[start + j];
        int2 e1 = csr[start + j + 1];
        float w0 = __int_as_float(e0.y);
        float w1 = __int_as_float(e1.y);
        float2 v0 = __half22float2(x1[(size_t)e0.x * 64 + lane]);
        float2 v1 = __half22float2(x1[(size_t)e1.x * 64 + lane]);
        acc.x = fmaf(w0, v0.x, acc.x);
        acc.y = fmaf(w0, v0.y, acc.y);
        acc.x = fmaf(w1, v1.x, acc.x);
        acc.y = fmaf(w1, v1.y, acc.y);
    }
    if (j < n) {
        int2 e0 = csr[start + j];
        float w0 = __int_as_float(e0.y);
        float2 v0 = __half22float2(x1[(size_t)e0.x * 64 + lane]);
        acc.x = fmaf(w0, v0.x, acc.x);
        acc.y = fmaf(w0, v0.y, acc.y);
    }
    float dv = dinv[d];
    float ws = dv * dv;
    float2 v = __half22float2(x1[(size_t)d * 64 + lane]);
    acc.x = fmaf(ws, v.x, acc.x);
    acc.y = fmaf(ws, v.y, acc.y);
    *reinterpret_cast<float2*>(agg2 + (size_t)d * HID + f0) = acc;
}

// ---------- fused dense tail, LDS-resident, 4-node x (4+4)-output register blocking ----
// r12 post-mortem: h0=tx*8 mapping put ws reads on banks (tx*8)%32 -> 4-way conflict
// (SQ_LDS_BANK_CONFLICT 1.32e7, VALUBusy 80->47%). Fix: split each thread's 8 outputs
// into two 4-float columns at tx*4 and 64+tx*4 -> bank stride 4, 16 lanes cover
// 0..31 twice = 2-way alias = free (m136). Same read/MAC counts, same occupancy.
__device__ __forceinline__ void fmad(float4& acc, float s, const float4 w) {
    acc.x = fmaf(s, w.x, acc.x);
    acc.y = fmaf(s, w.y, acc.y);
    acc.z = fmaf(s, w.z, acc.z);
    acc.w = fmaf(s, w.w, acc.w);
}
__device__ __forceinline__ float4 relu4(float4 v) {
    float4 r;
    r.x = fmaxf(v.x, 0.0f); r.y = fmaxf(v.y, 0.0f);
    r.z = fmaxf(v.z, 0.0f); r.w = fmaxf(v.w, 0.0f);
    return r;
}

__global__ void __launch_bounds__(256, 3) k_mlp(const float* __restrict__ agg2,
                                                const float* __restrict__ W2,
                                                const float* __restrict__ b2,
                                                const float* __restrict__ fc1w,
                                                const float* __restrict__ fc1b,
                                                const float* __restrict__ fc2w,
                                                const float* __restrict__ fc2b,
                                                float* __restrict__ out) {
    __shared__ float as_[TILE][HID + 4];   // activation tile, then x2 tile (33.8KB)
    __shared__ float ws[32][HID + 4];      // 32 staged weight rows (16.9KB)
    const int tid = threadIdx.x;
    const int tx = tid & 15;               // two output cols: hA=tx*4, hB=64+tx*4
    const int ty = tid >> 4;               // nodes ty*4 .. ty*4+3
    const int n0 = blockIdx.x * TILE;      // tail block: 32 valid nodes, guarded
    const int hA = tx * 4;
    const int hB = 64 + tx * 4;

    // stage activations: 64 rows x 128 floats = 2048 f4, 8 per thread (clamped rows)
    #pragma unroll
    for (int q = 0; q < 8; ++q) {
        int idx = (q * 256 + tid) * 4;
        int row = idx >> 7, col = idx & 127;
        int nr = n0 + row; if (nr >= NGRAPH) nr = NGRAPH - 1;
        *reinterpret_cast<float4*>(&as_[row][col]) =
            *reinterpret_cast<const float4*>(agg2 + (size_t)nr * HID + col);
    }

    // ---- phase A: x2 = relu(agg2 @ W2 + b2) ----
    float4 cA[4], cB[4];
    {
        float4 bA = *reinterpret_cast<const float4*>(b2 + hA);
        float4 bB = *reinterpret_cast<const float4*>(b2 + hB);
        #pragma unroll
        for (int r = 0; r < 4; ++r) { cA[r] = bA; cB[r] = bB; }
    }
    for (int ks = 0; ks < HID; ks += 32) {
        #pragma unroll
        for (int q = 0; q < 4; ++q) {
            int idx = (q * 256 + tid) * 4;
            int row = idx >> 7, col = idx & 127;
            *reinterpret_cast<float4*>(&ws[row][col]) =
                *reinterpret_cast<const float4*>(W2 + (size_t)(ks + row) * HID + col);
        }
        __syncthreads();                    // also covers as_ staging on ks==0
        #pragma unroll
        for (int k = 0; k < 32; k += 4) {
            float4 wA0 = *reinterpret_cast<const float4*>(&ws[k + 0][hA]);
            float4 wB0 = *reinterpret_cast<const float4*>(&ws[k + 0][hB]);
            float4 wA1 = *reinterpret_cast<const float4*>(&ws[k + 1][hA]);
            float4 wB1 = *reinterpret_cast<const float4*>(&ws[k + 1][hB]);
            float4 wA2 = *reinterpret_cast<const float4*>(&ws[k + 2][hA]);
            float4 wB2 = *reinterpret_cast<const float4*>(&ws[k + 2][hB]);
            float4 wA3 = *reinterpret_cast<const float4*>(&ws[k + 3][hA]);
            float4 wB3 = *reinterpret_cast<const float4*>(&ws[k + 3][hB]);
            #pragma unroll
            for (int r = 0; r < 4; ++r) {
                float4 a = *reinterpret_cast<const float4*>(&as_[ty * 4 + r][ks + k]);
                fmad(cA[r], a.x, wA0); fmad(cB[r], a.x, wB0);
                fmad(cA[r], a.y, wA1); fmad(cB[r], a.y, wB1);
                fmad(cA[r], a.z, wA2); fmad(cB[r], a.z, wB2);
                fmad(cA[r], a.w, wA3); fmad(cB[r], a.w, wB3);
            }
        }
        __syncthreads();                    // protect ws for next stage
    }
    // write x2 into as_ (all phase-A reads completed at the trailing sync)
    #pragma unroll
    for (int r = 0; r < 4; ++r) {
        *reinterpret_cast<float4*>(&as_[ty * 4 + r][hA]) = relu4(cA[r]);
        *reinterpret_cast<float4*>(&as_[ty * 4 + r][hB]) = relu4(cB[r]);
    }

    // ---- phase B: x3 = relu(x2 @ fc1w + fc1b) ----
    float4 dA[4], dB[4];
    {
        float4 bA = *reinterpret_cast<const float4*>(fc1b + hA);
        float4 bB = *reinterpret_cast<const float4*>(fc1b + hB);
        #pragma unroll
        for (int r = 0; r < 4; ++r) { dA[r] = bA; dB[r] = bB; }
    }
    for (int ks = 0; ks < HID; ks += 32) {
        #pragma unroll
        for (int q = 0; q < 4; ++q) {
            int idx = (q * 256 + tid) * 4;
            int row = idx >> 7, col = idx & 127;
            *reinterpret_cast<float4*>(&ws[row][col]) =
                *reinterpret_cast<const float4*>(fc1w + (size_t)(ks + row) * HID + col);
        }
        __syncthreads();                    // also makes x2 writes visible (ks==0)
        #pragma unroll
        for (int k = 0; k < 32; k += 4) {
            float4 wA0 = *reinterpret_cast<const float4*>(&ws[k + 0][hA]);
            float4 wB0 = *reinterpret_cast<const float4*>(&ws[k + 0][hB]);
            float4 wA1 = *reinterpret_cast<const float4*>(&ws[k + 1][hA]);
            float4 wB1 = *reinterpret_cast<const float4*>(&ws[k + 1][hB]);
            float4 wA2 = *reinterpret_cast<const float4*>(&ws[k + 2][hA]);
            float4 wB2 = *reinterpret_cast<const float4*>(&ws[k + 2][hB]);
            float4 wA3 = *reinterpret_cast<const float4*>(&ws[k + 3][hA]);
            float4 wB3 = *reinterpret_cast<const float4*>(&ws[k + 3][hB]);
            #pragma unroll
            for (int r = 0; r < 4; ++r) {
                float4 a = *reinterpret_cast<const float4*>(&as_[ty * 4 + r][ks + k]);
                fmad(dA[r], a.x, wA0); fmad(dB[r], a.x, wB0);
                fmad(dA[r], a.y, wA1); fmad(dB[r], a.y, wB1);
                fmad(dA[r], a.z, wA2); fmad(dB[r], a.z, wB2);
                fmad(dA[r], a.w, wA3); fmad(dB[r], a.w, wB3);
            }
        }
        __syncthreads();
    }

    // ---- phase C: out = x3 @ fc2w + fc2b (reduce over 16 tx lanes) ----
    float4 wqA = *reinterpret_cast<const float4*>(fc2w + hA);
    float4 wqB = *reinterpret_cast<const float4*>(fc2w + hB);
    float p[4];
    #pragma unroll
    for (int r = 0; r < 4; ++r) {
        float4 rA = relu4(dA[r]);
        float4 rB = relu4(dB[r]);
        p[r] = rA.x * wqA.x + rA.y * wqA.y + rA.z * wqA.z + rA.w * wqA.w
             + rB.x * wqB.x + rB.y * wqB.y + rB.z * wqB.z + rB.w * wqB.w;
    }
    #pragma unroll
    for (int m = 1; m < 16; m <<= 1) {     // xor-mask < 16 stays within the tx group
        #pragma unroll
        for (int r = 0; r < 4; ++r) p[r] += __shfl_xor(p[r], m);
    }
    if (tx == 0) {
        float bq = fc2b[0];
        int nb = n0 + ty * 4;
        #pragma unroll
        for (int r = 0; r < 4; ++r)
            if (nb + r < NGRAPH) out[nb + r] = p[r] + bq;
    }
}

extern "C" void kernel_launch(void* const* d_in, const int* in_sizes, int n_in,
                              void* d_out, int out_size, void* d_ws, size_t ws_size,
                              hipStream_t stream) {
    const float* obs  = (const float*)d_in[0];
    const int*   ei   = (const int*)d_in[1];
    const float* W1   = (const float*)d_in[2];
    const float* b1   = (const float*)d_in[3];
    const float* W2   = (const float*)d_in[4];
    const float* b2   = (const float*)d_in[5];
    const float* fc1w = (const float*)d_in[6];
    const float* fc1b = (const float*)d_in[7];
    const float* fc2w = (const float*)d_in[8];
    const float* fc2b = (const float*)d_in[9];
    float* out = (float*)d_out;

    char* base = (char*)d_ws;
    size_t off = 0;
    auto take = [&](size_t bytes) {
        char* p = base + off;
        off += (bytes + 255) & ~(size_t)255;
        return p;
    };
    int*    deg     = (int*)take((size_t)NGRAPH * 4);
    int*    rowptr  = (int*)take((size_t)NGRAPH * 4);
    int*    fill    = (int*)take((size_t)NGRAPH * 4);
    int*    sums    = (int*)take((size_t)NBLK * 4);
    float*  dinv    = (float*)take((size_t)NGRAPH * 4);
    int2*   csr     = (int2*)take((size_t)NEDGE * 8);
    float*  comb    = (float*)take((size_t)NGRAPH * 7 * 4);
    __half* x1      = (__half*)take((size_t)NGRAPH * HID * 2);
    float*  agg2    = (float*)take((size_t)NGRAPH * HID * 4);
    int*    flag    = (int*)take(256);

    k_prep<<<(NGRAPH + 255) / 256, 256, 0, stream>>>(obs, ei, comb, deg, fill, flag);
    k_deg<<<(NEDGE + 255) / 256, 256, 0, stream>>>(ei, flag, deg);
    k_scan1<<<NBLK, SCAN_B, 0, stream>>>(deg, rowptr, sums, dinv);
    k_scan2<<<1, 256, 0, stream>>>(sums);
    k_scan3<<<NBLK, SCAN_B, 0, stream>>>(rowptr, sums);
    k_fill<<<(NEDGE + 255) / 256, 256, 0, stream>>>(ei, flag, dinv, rowptr, fill, csr);
    k_gcn1<<<NGRAPH / 32, 256, 0, stream>>>(rowptr, deg, csr, dinv,
                                            comb, W1, b1, x1);
    k_agg2<<<NGRAPH / 4, 256, 0, stream>>>(rowptr, deg, csr, dinv,
                                           (const __half2*)x1, agg2);
    k_mlp<<<(NGRAPH + TILE - 1) / TILE, 256, 0, stream>>>(agg2, W2, b2,
                                                          fc1w, fc1b,
                                                          fc2w, fc2b, out);
}